// Round 1
// baseline (161.981 us; speedup 1.0000x reference)
//
#include <hip/hip_runtime.h>

#define BQ 4
#define HH 64
#define WW 64
#define NN 4096
#define DZc 128
#define KSPLIT 4
#define KRANGE (NN/KSPLIT)   // 1024
#define BK 64
#define NKT (KRANGE/BK)      // 16

typedef short v8s __attribute__((ext_vector_type(8)));
typedef float v4f __attribute__((ext_vector_type(4)));

__device__ __forceinline__ unsigned rnd_bf(float f){
  union { float f; unsigned u; } c; c.f = f;
  return c.u + 0x8000u;   // round-half-up to bf16 (no bias concern at this magnitude)
}

__device__ __forceinline__ unsigned pack2(float lo, float hi){
#if __has_builtin(__builtin_amdgcn_perm)
  return __builtin_amdgcn_perm(rnd_bf(hi), rnd_bf(lo), 0x07060302u);
#else
  return (rnd_bf(lo) >> 16) | (rnd_bf(hi) & 0xFFFF0000u);
#endif
}

__device__ __forceinline__ float fexp2(float x){
#if __has_builtin(__builtin_amdgcn_exp2f)
  return __builtin_amdgcn_exp2f(x);
#else
  return exp2f(x);
#endif
}

__global__ void init_out_kernel(const float4* __restrict__ zc_on,
                                const int* __restrict__ ignore,
                                float4* __restrict__ out){
  int i = blockIdx.x * blockDim.x + threadIdx.x;
  float4 v = zc_on[i];
  if (ignore[0]) { v.x = 0.f; v.y = 0.f; v.z = 0.f; v.w = 0.f; }
  out[i] = v;
}

// Block tile: 128 m-rows (16 iy x 8 ix patch) x 128 d, K-split 4-way over N.
// 256 threads = 4 waves in 2x2 (m-half x d-half), each wave 64m x 64d via
// 16x16x32 bf16 MFMA (4 m-tiles x 4 d-tiles, acc 64 VGPR/lane).
__global__ void setconv_gemm_kernel(const float* __restrict__ xc_off,
                                    const float* __restrict__ xc_on,
                                    const float* __restrict__ zc_off,
                                    const float* __restrict__ lsp,
                                    float* __restrict__ out)
{
  __shared__ float gtab[24][68];            // rows 0..15: gy(py), 16..23: gx(px); pad 68
  __shared__ unsigned short zt[128][72];    // Z^T bf16 [d][k], pad 72 (row 144B, 16B-aligned)
  unsigned* const ztw = (unsigned*)&zt[0][0];

  const int tid = threadIdx.x;
  const int bid = blockIdx.x;
  const int ks  = bid & (KSPLIT - 1);
  const int mt  = (bid >> 2) & 31;
  const int b   = bid >> 7;
  const int iy0 = (mt >> 3) * 16;
  const int ix0 = (mt & 7) * 8;

  const float lsy = 1e-5f + log1pf(expf(lsp[0]));
  const float lsx = 1e-5f + log1pf(expf(lsp[1]));
  const float LOG2E = 1.44269504088896340736f;
  const float ay = -0.5f * LOG2E / (lsy * lsy);
  const float ax = -0.5f * LOG2E / (lsx * lsx);

  // per-thread g-table constants: rows (tid>>6)+4i; i<4 -> gy rows (static), i>=4 -> gx rows
  float gc[6], ga[6];
  #pragma unroll
  for (int i = 0; i < 6; ++i){
    int row = (tid >> 6) + 4 * i;
    if (i < 4){
      gc[i] = xc_on[((b * HH + iy0 + row) * WW + 0) * 2 + 0];   // y coord of grid row
      ga[i] = ay;
    } else {
      gc[i] = xc_on[(b * HH * WW + (ix0 + row - 16)) * 2 + 1];  // x coord of grid col
      ga[i] = ax;
    }
  }
  const int gk = tid & 63;

  // z-staging lane mapping: dp-low=lane[0:3] (coalesce), t-low=lane[4:5] (bank spread)
  const int dp = (tid & 15) | (((tid >> 6) & 3) << 4);
  const int tl = (tid >> 4) & 3;

  const int lane = tid & 63;
  const int wv = tid >> 6;
  const int wm = wv >> 1, wd = wv & 1;
  const int i16 = lane & 15, quad = lane >> 4;
  const int px = lane & 7, pyb = (lane >> 3) & 1;

  v4f acc[4][4];
  #pragma unroll
  for (int t = 0; t < 4; ++t)
    #pragma unroll
    for (int d = 0; d < 4; ++d)
      acc[t][d] = (v4f){0.f, 0.f, 0.f, 0.f};

  const float* xb = xc_off + (size_t)b * NN * 2;
  const float* zb = zc_off + (size_t)b * NN * DZc;

  #pragma unroll 1
  for (int kt = 0; kt < NKT; ++kt){
    const int n0 = ks * KRANGE + kt * BK;
    __syncthreads();

    // ---- g tables: 24 rows x 64 k, 6 exp2/thread
    {
      float2 xo = *(const float2*)&xb[(size_t)(n0 + gk) * 2];
      #pragma unroll
      for (int i = 0; i < 6; ++i){
        float x = (i < 4) ? xo.x : xo.y;
        float d = gc[i] - x;
        gtab[(tid >> 6) + 4 * i][gk] = fexp2(ga[i] * d * d);
      }
    }

    // ---- Z tile -> bf16 transposed LDS (float2 loads of n,n+1 rows; packed b32 writes)
    #pragma unroll
    for (int p = 0; p < 8; ++p){
      int t = tl | (p << 2);                       // n-pair index 0..31
      const float* src = zb + (size_t)(n0 + 2 * t) * DZc + 2 * dp;
      float2 lo = *(const float2*)src;             // row n
      float2 hi = *(const float2*)(src + DZc);     // row n+1
      ztw[(2 * dp)     * 36 + t] = pack2(lo.x, hi.x);
      ztw[(2 * dp + 1) * 36 + t] = pack2(lo.y, hi.y);
    }
    __syncthreads();

    // ---- MFMA: A = gy*gx built in registers, B from zt
    #pragma unroll
    for (int kstep = 0; kstep < 2; ++kstep){
      const int kq = kstep * 32 + quad * 8;
      const float4 gxa = *(const float4*)&gtab[16 + px][kq];
      const float4 gxb = *(const float4*)&gtab[16 + px][kq + 4];
      v8s bf[4];
      #pragma unroll
      for (int dt = 0; dt < 4; ++dt)
        bf[dt] = *(const v8s*)&zt[wd * 64 + dt * 16 + i16][kq];
      #pragma unroll
      for (int t = 0; t < 4; ++t){
        const int py = wm * 8 + t * 2 + pyb;
        const float4 gya = *(const float4*)&gtab[py][kq];
        const float4 gyb = *(const float4*)&gtab[py][kq + 4];
        union { unsigned u[4]; v8s v; } af;
        af.u[0] = pack2(gya.x * gxa.x, gya.y * gxa.y);
        af.u[1] = pack2(gya.z * gxa.z, gya.w * gxa.w);
        af.u[2] = pack2(gyb.x * gxb.x, gyb.y * gxb.y);
        af.u[3] = pack2(gyb.z * gxb.z, gyb.w * gxb.w);
        #pragma unroll
        for (int dt = 0; dt < 4; ++dt)
          acc[t][dt] = __builtin_amdgcn_mfma_f32_16x16x32_bf16(af.v, bf[dt], acc[t][dt], 0, 0, 0);
      }
    }
  }

  // ---- epilogue: atomic accumulate K-split partials
  #pragma unroll
  for (int t = 0; t < 4; ++t){
    #pragma unroll
    for (int dt = 0; dt < 4; ++dt){
      const int d = wd * 64 + dt * 16 + i16;
      #pragma unroll
      for (int r = 0; r < 4; ++r){
        const int ml = wm * 64 + t * 16 + quad * 4 + r;   // C/D row = quad*4+reg
        const int iy = iy0 + (ml >> 3);
        const int ix = ix0 + (ml & 7);
        unsafeAtomicAdd(&out[((b * HH + iy) * WW + ix) * DZc + d], acc[t][dt][r]);
      }
    }
  }
}

extern "C" void kernel_launch(void* const* d_in, const int* in_sizes, int n_in,
                              void* d_out, int out_size, void* d_ws, size_t ws_size,
                              hipStream_t stream){
  const float* xc_off = (const float*)d_in[0];
  const float* xc_on  = (const float*)d_in[1];
  const float* zc_off = (const float*)d_in[2];
  const float* zc_on  = (const float*)d_in[3];
  const float* lsp    = (const float*)d_in[4];
  const int*   ign    = (const int*)d_in[5];
  float* out = (float*)d_out;

  // out := ignore ? 0 : zc_on_grid   (then GEMM atomically accumulates)
  init_out_kernel<<<out_size / 1024, 256, 0, stream>>>((const float4*)zc_on, ign, (float4*)out);
  setconv_gemm_kernel<<<BQ * 32 * KSPLIT, 256, 0, stream>>>(xc_off, xc_on, zc_off, lsp, out);
}